// Round 3
// baseline (245.603 us; speedup 1.0000x reference)
//
#include <hip/hip_runtime.h>

typedef unsigned short u16;
typedef __attribute__((ext_vector_type(8))) short bf16x8;
typedef __attribute__((ext_vector_type(16))) float f32x16;

#define HID 1024
#define BATCH 4096
#define K3 6144   // 3 * 2048 (hi | lo | hi split blocks)
#define NGATE 4096
#define BK 32
#define NT 192    // K3 / BK

// ---------- bf16 helpers ----------
__device__ __forceinline__ u16 f2bf(float f) {
  unsigned int u = __float_as_uint(f);
  u += 0x7FFFu + ((u >> 16) & 1u);   // RNE
  return (u16)(u >> 16);
}
__device__ __forceinline__ float bf2f(u16 h) {
  return __uint_as_float(((unsigned int)h) << 16);
}

__device__ __forceinline__ void load16_to_lds(const void* g, void* l) {
  __builtin_amdgcn_global_load_lds(
      (const __attribute__((address_space(1))) unsigned int*)g,
      (__attribute__((address_space(3))) unsigned int*)l, 16, 0, 0);
}

__device__ __forceinline__ float sigmoid_f(float x) {
  return 1.f / (1.f + __expf(-x));
}
__device__ __forceinline__ float tanh_f(float x) {
  return 1.f - 2.f / (__expf(2.f * x) + 1.f);
}

// ---------- pack activations: Bt[m][k'] = [hi(x|h) | lo(x|h) | hi(x|h)] ----------
__global__ void pack_act(const float* __restrict__ x, const float* __restrict__ h,
                         u16* __restrict__ Bt) {
  size_t idx = (size_t)blockIdx.x * 256 + threadIdx.x;
  int m  = (int)(idx >> 9);
  int kq = (int)(idx & 511) << 2;
  const float* src = (kq < 1024) ? (x + (size_t)m * 1024 + kq)
                                 : (h + (size_t)m * 1024 + (kq - 1024));
  float4 v = *(const float4*)src;
  ushort4 hi, lo;
  hi.x = f2bf(v.x); lo.x = f2bf(v.x - bf2f(hi.x));
  hi.y = f2bf(v.y); lo.y = f2bf(v.y - bf2f(hi.y));
  hi.z = f2bf(v.z); lo.z = f2bf(v.z - bf2f(hi.z));
  hi.w = f2bf(v.w); lo.w = f2bf(v.w - bf2f(hi.w));
  u16* row = Bt + (size_t)m * K3;
  *(ushort4*)(row + kq)        = hi;
  *(ushort4*)(row + 2048 + kq) = lo;
  *(ushort4*)(row + 4096 + kq) = hi;
}

// ---------- pack weights: P[n=4h+g][k'] = [hi(W;U) | hi(W;U) | lo(W;U)] ----------
__global__ void pack_w(const float* __restrict__ Wf, const float* __restrict__ Wi,
                       const float* __restrict__ Wc, const float* __restrict__ Wo,
                       const float* __restrict__ Uf, const float* __restrict__ Ui,
                       const float* __restrict__ Uc, const float* __restrict__ Uo,
                       u16* __restrict__ P) {
  __shared__ float ldsT[32][33];
  int bid = blockIdx.x;
  int mat = bid >> 10;
  int tid = bid & 1023;
  int k0 = (tid >> 5) << 5;
  int h0 = (tid & 31) << 5;
  int g = mat & 3;
  const float* S;
  {
    const float* a = (mat & 1) ? ((mat & 2) ? Wo : Wi) : ((mat & 2) ? Wc : Wf);
    const float* b = (mat & 1) ? ((mat & 2) ? Uo : Ui) : ((mat & 2) ? Uc : Uf);
    S = (mat & 4) ? b : a;
  }
  int kbase = (mat & 4) ? 1024 : 0;

  int t = threadIdx.x;
  {
    int r0 = t >> 5;
    int c  = t & 31;
#pragma unroll
    for (int j = 0; j < 4; ++j)
      ldsT[c][r0 + 8 * j] = S[(size_t)(k0 + r0 + 8 * j) * 1024 + h0 + c];
  }
  __syncthreads();
  {
    int c  = t >> 3;
    int kq = (t & 7) << 2;
    int n  = ((h0 + c) << 2) + g;
    float v0 = ldsT[c][kq + 0], v1 = ldsT[c][kq + 1];
    float v2 = ldsT[c][kq + 2], v3 = ldsT[c][kq + 3];
    ushort4 hi, lo;
    hi.x = f2bf(v0); lo.x = f2bf(v0 - bf2f(hi.x));
    hi.y = f2bf(v1); lo.y = f2bf(v1 - bf2f(hi.y));
    hi.z = f2bf(v2); lo.z = f2bf(v2 - bf2f(hi.z));
    hi.w = f2bf(v3); lo.w = f2bf(v3 - bf2f(hi.w));
    u16* base = P + (size_t)n * K3 + kbase + k0 + kq;
    *(ushort4*)(base)        = hi;
    *(ushort4*)(base + 2048) = hi;
    *(ushort4*)(base + 4096) = lo;
  }
}

// ---------- pack biases ----------
__global__ void pack_bias(const float* __restrict__ bf, const float* __restrict__ bi,
                          const float* __restrict__ bc, const float* __restrict__ bo,
                          float* __restrict__ bcat) {
  int i = blockIdx.x * 256 + threadIdx.x;
  if (i < NGATE) {
    int h = i >> 2, g = i & 3;
    const float* b = (g == 0) ? bf : (g == 1) ? bi : (g == 2) ? bc : bo;
    bcat[i] = b[h];
  }
}

// ---------- fused GEMM + LSTM epilogue ----------
// 256x256 tile, BK=32, 8 waves (2n x 4m), 32x32x16 MFMA, 4-deep LDS ring,
// counted vmcnt(8), per-K-tile 2-phase interleave, setprio around MFMA.
__global__ __launch_bounds__(512, 2) void lstm_gemm(
    const u16* __restrict__ P, const u16* __restrict__ Bt,
    const float* __restrict__ bcat, const float* __restrict__ c_prev,
    float* __restrict__ out) {
  __shared__ __align__(16) u16 As[4][256 * BK];   // 64 KiB
  __shared__ __align__(16) u16 Bs[4][256 * BK];   // 64 KiB

  const int t = threadIdx.x;
  const int w = t >> 6;
  const int l = t & 63;

  // XCD-chunked bijective block swizzle (256 = 8 XCD * 32)
  const int bid = blockIdx.x;
  const int swz = ((bid & 7) << 5) + (bid >> 3);
  const int n0 = (swz & 15) << 8;     // gate-dim tile base
  const int m0 = (swz >> 4) << 8;     // batch tile base

  const int wm = w >> 2;              // 0..1 : wave n-half
  const int wn = w & 3;               // 0..3 : wave m-quarter

  // ---- staging: 4 x global_load_lds per K-tile per wave, swizzled source ----
  const int srow = t >> 2;                               // 0..127
  const int ssl  = (((t & 3) ^ ((srow >> 1) & 3)) << 3); // swizzled 8-u16 slot
  const u16* gA0 = P  + (size_t)(n0 + srow)       * K3 + ssl;
  const u16* gA1 = P  + (size_t)(n0 + 128 + srow) * K3 + ssl;
  const u16* gB0 = Bt + (size_t)(m0 + srow)       * K3 + ssl;
  const u16* gB1 = Bt + (size_t)(m0 + 128 + srow) * K3 + ssl;
  const int ldw0 = w << 9;            // wave-uniform LDS dest (u16)
  const int ldw1 = 4096 + (w << 9);

  // ---- fragment read offsets (loop-invariant, swizzled) ----
  // 32x32x16 A/B operand: lane holds row (l&31), 8 consecutive k at (l>>5)*8.
  const int lr = l & 31;
  const int hi = l >> 5;
  int offA0[4], offA1[4], offB0[2], offB1[2];
#pragma unroll
  for (int i = 0; i < 4; ++i) {
    int ar = (wm << 7) + i * 32 + lr;
    offA0[i] = ar * BK + (((0 + hi) ^ ((ar >> 1) & 3)) << 3);   // k-slice 0
    offA1[i] = ar * BK + (((2 + hi) ^ ((ar >> 1) & 3)) << 3);   // k-slice 1
  }
#pragma unroll
  for (int j = 0; j < 2; ++j) {
    int br = (wn << 6) + j * 32 + lr;
    offB0[j] = br * BK + (((0 + hi) ^ ((br >> 1) & 3)) << 3);
    offB1[j] = br * BK + (((2 + hi) ^ ((br >> 1) & 3)) << 3);
  }

  f32x16 acc[4][2];
#pragma unroll
  for (int i = 0; i < 4; ++i)
#pragma unroll
    for (int j = 0; j < 2; ++j)
#pragma unroll
      for (int r = 0; r < 16; ++r) acc[i][j][r] = 0.f;

  // ---- prologue: stage K-tiles 0,1,2 into bufs 0,1,2 ----
#pragma unroll
  for (int pt = 0; pt < 3; ++pt) {
    const int kt = pt * BK;
    load16_to_lds(gA0 + kt, &As[pt][ldw0]);
    load16_to_lds(gA1 + kt, &As[pt][ldw1]);
    load16_to_lds(gB0 + kt, &Bs[pt][ldw0]);
    load16_to_lds(gB1 + kt, &Bs[pt][ldw1]);
  }
  asm volatile("s_waitcnt vmcnt(8)" ::: "memory");   // tile 0 landed
  __builtin_amdgcn_s_barrier();

  // ---- main loop: 192 K-tiles, unrolled x4 for static ring indices ----
  for (int t4 = 0; t4 < NT; t4 += 4) {
#pragma unroll
    for (int u = 0; u < 4; ++u) {
      const int tt  = t4 + u;
      const int pfi = tt + 3;
      const int pkt = (pfi < NT ? pfi : NT - 1) * BK;  // clamped tail prefetch
      const int pc  = (u + 3) & 3;

      // ---- phase A: k-slice 0, all B frags ----
      bf16x8 aF[4], bF0[2], bF1[2];
#pragma unroll
      for (int i = 0; i < 4; ++i) aF[i] = *(const bf16x8*)&As[u][offA0[i]];
#pragma unroll
      for (int j = 0; j < 2; ++j) {
        bF0[j] = *(const bf16x8*)&Bs[u][offB0[j]];
        bF1[j] = *(const bf16x8*)&Bs[u][offB1[j]];
      }
      load16_to_lds(gA0 + pkt, &As[pc][ldw0]);
      load16_to_lds(gA1 + pkt, &As[pc][ldw1]);
      __builtin_amdgcn_s_barrier();
      asm volatile("s_waitcnt lgkmcnt(0)" ::: "memory");
      __builtin_amdgcn_sched_barrier(0);
      __builtin_amdgcn_s_setprio(1);
#pragma unroll
      for (int i = 0; i < 4; ++i)
#pragma unroll
        for (int j = 0; j < 2; ++j)
          acc[i][j] = __builtin_amdgcn_mfma_f32_32x32x16_bf16(aF[i], bF0[j], acc[i][j], 0, 0, 0);
      __builtin_amdgcn_s_setprio(0);
      __builtin_amdgcn_s_barrier();

      // ---- phase B: k-slice 1 (B frags reused from registers) ----
      bf16x8 aG[4];
#pragma unroll
      for (int i = 0; i < 4; ++i) aG[i] = *(const bf16x8*)&As[u][offA1[i]];
      load16_to_lds(gB0 + pkt, &Bs[pc][ldw0]);
      load16_to_lds(gB1 + pkt, &Bs[pc][ldw1]);
      __builtin_amdgcn_s_barrier();
      asm volatile("s_waitcnt lgkmcnt(0)" ::: "memory");
      __builtin_amdgcn_sched_barrier(0);
      __builtin_amdgcn_s_setprio(1);
#pragma unroll
      for (int i = 0; i < 4; ++i)
#pragma unroll
        for (int j = 0; j < 2; ++j)
          acc[i][j] = __builtin_amdgcn_mfma_f32_32x32x16_bf16(aG[i], bF1[j], acc[i][j], 0, 0, 0);
      __builtin_amdgcn_s_setprio(0);
      // counted drain: tile tt+1 landed; tiles tt+2,tt+3 (8 loads) in flight
      asm volatile("s_waitcnt vmcnt(8)" ::: "memory");
      __builtin_amdgcn_s_barrier();
    }
  }

  // ---- epilogue: C/D 32x32 layout: col=l&31, row=(reg&3)+8*(reg>>2)+4*hi ----
  // reg quad 4q..4q+3 = gates f,i,c,o of h = (n_base+i*32)/4 + 2q + hi
  const int n_base = n0 + (wm << 7);
  const int m_base = m0 + (wn << 6);
#pragma unroll
  for (int i = 0; i < 4; ++i)
#pragma unroll
    for (int j = 0; j < 2; ++j) {
      const int m = m_base + j * 32 + lr;
#pragma unroll
      for (int q = 0; q < 4; ++q) {
        int nf = n_base + i * 32 + 8 * q + 4 * hi;
        int h  = nf >> 2;
        float4 b4 = *(const float4*)&bcat[nf];
        float ft = sigmoid_f(acc[i][j][4 * q + 0] + b4.x);
        float it = sigmoid_f(acc[i][j][4 * q + 1] + b4.y);
        float ct = tanh_f   (acc[i][j][4 * q + 2] + b4.z);
        float ot = sigmoid_f(acc[i][j][4 * q + 3] + b4.w);
        float cp = c_prev[(size_t)m * HID + h];
        float cn = ft * cp + it * ct;
        out[(size_t)m * HID + h] = ot * tanh_f(cn);
      }
    }
}

extern "C" void kernel_launch(void* const* d_in, const int* in_sizes, int n_in,
                              void* d_out, int out_size, void* d_ws, size_t ws_size,
                              hipStream_t stream) {
  const float* x  = (const float*)d_in[0];
  const float* hp = (const float*)d_in[1];
  const float* cp = (const float*)d_in[2];
  const float* Wf = (const float*)d_in[3];
  const float* Wi = (const float*)d_in[4];
  const float* Wc = (const float*)d_in[5];
  const float* Wo = (const float*)d_in[6];
  const float* Uf = (const float*)d_in[7];
  const float* Ui = (const float*)d_in[8];
  const float* Uc = (const float*)d_in[9];
  const float* Uo = (const float*)d_in[10];
  const float* bf = (const float*)d_in[11];
  const float* bi = (const float*)d_in[12];
  const float* bc = (const float*)d_in[13];
  const float* bo = (const float*)d_in[14];

  const size_t P_BYTES  = (size_t)NGATE * K3 * 2;
  const size_t BT_BYTES = (size_t)BATCH * K3 * 2;
  u16*   Pw   = (u16*)d_ws;
  u16*   Bt   = (u16*)((char*)d_ws + P_BYTES);
  float* bcat = (float*)((char*)d_ws + P_BYTES + BT_BYTES);
  float* out  = (float*)d_out;

  pack_act <<<dim3(8192), dim3(256), 0, stream>>>(x, hp, Bt);
  pack_w   <<<dim3(8192), dim3(256), 0, stream>>>(Wf, Wi, Wc, Wo, Uf, Ui, Uc, Uo, Pw);
  pack_bias<<<dim3(16),   dim3(256), 0, stream>>>(bf, bi, bc, bo, bcat);
  lstm_gemm<<<dim3(256),  dim3(512), 0, stream>>>(Pw, Bt, bcat, cp, out);
}

// Round 4
// 235.556 us; speedup vs baseline: 1.0426x; 1.0426x over previous
//
#include <hip/hip_runtime.h>

typedef unsigned short u16;
typedef signed char i8;
typedef __attribute__((ext_vector_type(4))) int i32x4;

#define HID 1024
#define BATCH 4096
#define K8 8192    // 4 * 2048 i8 blocks: [a|a|b|b] x, [a|b|a|b] w
#define NGATE 4096
#define BKB 64     // 64 i8 cols per K-tile = 64 B rows (same bytes as R2's BK=32 bf16)
#define NT 128     // K8 / BKB
#define SCALE (6.5f / 127.0f)
#define INV_S (127.0f / 6.5f)

__device__ __forceinline__ void load16_to_lds(const void* g, void* l) {
  __builtin_amdgcn_global_load_lds(
      (const __attribute__((address_space(1))) unsigned int*)g,
      (__attribute__((address_space(3))) unsigned int*)l, 16, 0, 0);
}

__device__ __forceinline__ float sigmoid_f(float x) {
  return 1.f / (1.f + __expf(-x));
}
__device__ __forceinline__ float tanh_f(float x) {
  return 1.f - 2.f / (__expf(2.f * x) + 1.f);
}

__device__ __forceinline__ void quant2(float v, int& a, int& b) {
  float va = v * INV_S;
  a = __float2int_rn(va);
  a = max(-127, min(127, a));
  float r1 = va - (float)a;
  b = __float2int_rn(r1 * 254.f);
  b = max(-127, min(127, b));
}

// ---------- pack activations: Bt[m][k'] = [a | a | b | b] ----------
__global__ void pack_act(const float* __restrict__ x, const float* __restrict__ h,
                         i8* __restrict__ Bt) {
  size_t idx = (size_t)blockIdx.x * 256 + threadIdx.x;  // 4096 rows * 512 quads
  int m  = (int)(idx >> 9);
  int kq = (int)(idx & 511) << 2;
  const float* src = (kq < 1024) ? (x + (size_t)m * 1024 + kq)
                                 : (h + (size_t)m * 1024 + (kq - 1024));
  float4 v = *(const float4*)src;
  int a0, b0, a1, b1, a2, b2, a3, b3;
  quant2(v.x, a0, b0); quant2(v.y, a1, b1);
  quant2(v.z, a2, b2); quant2(v.w, a3, b3);
  char4 ca = make_char4((i8)a0, (i8)a1, (i8)a2, (i8)a3);
  char4 cb = make_char4((i8)b0, (i8)b1, (i8)b2, (i8)b3);
  i8* row = Bt + (size_t)m * K8;
  *(char4*)(row + kq)        = ca;
  *(char4*)(row + 2048 + kq) = ca;
  *(char4*)(row + 4096 + kq) = cb;
  *(char4*)(row + 6144 + kq) = cb;
}

// ---------- pack weights (transposed): P[n=4h+g][k'] = [a | b | a | b] ----------
__global__ void pack_w(const float* __restrict__ Wf, const float* __restrict__ Wi,
                       const float* __restrict__ Wc, const float* __restrict__ Wo,
                       const float* __restrict__ Uf, const float* __restrict__ Ui,
                       const float* __restrict__ Uc, const float* __restrict__ Uo,
                       i8* __restrict__ P) {
  __shared__ float ldsT[32][33];
  int bid = blockIdx.x;
  int mat = bid >> 10;            // 0..7 : g = mat&3, isU = mat>>2
  int tid = bid & 1023;
  int k0 = (tid >> 5) << 5;
  int h0 = (tid & 31) << 5;
  int g = mat & 3;
  const float* S;
  {
    const float* a = (mat & 1) ? ((mat & 2) ? Wo : Wi) : ((mat & 2) ? Wc : Wf);
    const float* b = (mat & 1) ? ((mat & 2) ? Uo : Ui) : ((mat & 2) ? Uc : Uf);
    S = (mat & 4) ? b : a;
  }
  int kbase = (mat & 4) ? 1024 : 0;

  int t = threadIdx.x;
  {
    int r0 = t >> 5;
    int c  = t & 31;
#pragma unroll
    for (int j = 0; j < 4; ++j)
      ldsT[c][r0 + 8 * j] = S[(size_t)(k0 + r0 + 8 * j) * 1024 + h0 + c];
  }
  __syncthreads();
  {
    int c  = t >> 3;
    int kq = (t & 7) << 2;
    int n  = ((h0 + c) << 2) + g;
    int a0, b0, a1, b1, a2, b2, a3, b3;
    quant2(ldsT[c][kq + 0], a0, b0);
    quant2(ldsT[c][kq + 1], a1, b1);
    quant2(ldsT[c][kq + 2], a2, b2);
    quant2(ldsT[c][kq + 3], a3, b3);
    char4 ca = make_char4((i8)a0, (i8)a1, (i8)a2, (i8)a3);
    char4 cb = make_char4((i8)b0, (i8)b1, (i8)b2, (i8)b3);
    i8* base = P + (size_t)n * K8 + kbase + k0 + kq;
    *(char4*)(base)        = ca;
    *(char4*)(base + 2048) = cb;
    *(char4*)(base + 4096) = ca;
    *(char4*)(base + 6144) = cb;
  }
}

// ---------- pack biases: bcat[4h+g] = b_g[h] ----------
__global__ void pack_bias(const float* __restrict__ bf, const float* __restrict__ bi,
                          const float* __restrict__ bc, const float* __restrict__ bo,
                          float* __restrict__ bcat) {
  int i = blockIdx.x * 256 + threadIdx.x;
  if (i < NGATE) {
    int h = i >> 2, g = i & 3;
    const float* b = (g == 0) ? bf : (g == 1) ? bi : (g == 2) ? bc : bo;
    bcat[i] = b[h];
  }
}

// ---------- fused i8 GEMM + LSTM epilogue ----------
// Byte-identical LDS/staging/swizzle geometry to the proven bf16 R2 kernel;
// MFMA = i32_16x16x64_i8; 3 acc groups by scale (1, 1/254, 1/254^2).
__global__ __launch_bounds__(512, 2) void lstm_gemm(
    const i8* __restrict__ P, const i8* __restrict__ Bt,
    const float* __restrict__ bcat, const float* __restrict__ c_prev,
    float* __restrict__ out) {
  __shared__ __align__(16) i8 As[4][256 * BKB];   // 64 KiB
  __shared__ __align__(16) i8 Bs[4][256 * BKB];   // 64 KiB

  const int t = threadIdx.x;
  const int w = t >> 6;
  const int l = t & 63;

  const int bid = blockIdx.x;
  const int swz = ((bid & 7) << 5) + (bid >> 3);   // XCD-chunked, 256 = 8*32
  const int n0 = (swz & 15) << 8;
  const int m0 = (swz >> 4) << 8;

  const int wm = w >> 2;
  const int wn = w & 3;

  // staging (identical bytes to R2): row t>>2, 16B slot (t&3) ^ ((row>>1)&3)
  const int srow = t >> 2;
  const int ssl  = (((t & 3) ^ ((srow >> 1) & 3)) << 4);
  const i8* gA0 = P  + (size_t)(n0 + srow)       * K8 + ssl;
  const i8* gA1 = P  + (size_t)(n0 + 128 + srow) * K8 + ssl;
  const i8* gB0 = Bt + (size_t)(m0 + srow)       * K8 + ssl;
  const i8* gB1 = Bt + (size_t)(m0 + 128 + srow) * K8 + ssl;
  const int ldw0 = w << 10;             // w * 1024 B
  const int ldw1 = 8192 + (w << 10);

  const int fr = l & 15;
  const int sl = l >> 4;
  int offA[8], offB[4];
#pragma unroll
  for (int i = 0; i < 8; ++i) {
    int ar = (wm << 7) + i * 16 + fr;
    offA[i] = ar * BKB + ((sl ^ ((ar >> 1) & 3)) << 4);
  }
#pragma unroll
  for (int j = 0; j < 4; ++j) {
    int br = (wn << 6) + j * 16 + fr;
    offB[j] = br * BKB + ((sl ^ ((br >> 1) & 3)) << 4);
  }

  i32x4 accH[4][4], accM[4][4], accL[4][4];
#pragma unroll
  for (int i = 0; i < 4; ++i)
#pragma unroll
    for (int j = 0; j < 4; ++j) {
      accH[i][j] = (i32x4){0, 0, 0, 0};
      accM[i][j] = (i32x4){0, 0, 0, 0};
      accL[i][j] = (i32x4){0, 0, 0, 0};
    }

  // prologue: stage K-tiles 0,1,2
#pragma unroll
  for (int pt = 0; pt < 3; ++pt) {
    const int kt = pt * BKB;
    load16_to_lds(gA0 + kt, &As[pt][ldw0]);
    load16_to_lds(gA1 + kt, &As[pt][ldw1]);
    load16_to_lds(gB0 + kt, &Bs[pt][ldw0]);
    load16_to_lds(gB1 + kt, &Bs[pt][ldw1]);
  }
  asm volatile("s_waitcnt vmcnt(8)" ::: "memory");
  __builtin_amdgcn_s_barrier();

  // one K-tile body; ring slot = tt&3, prefetch tt+3, counted vmcnt(8)
#define KTILE_BODY(ACC, tt, u)                                                   \
  {                                                                              \
    const int pfi = (tt) + 3;                                                    \
    const int pkt = (pfi < NT ? pfi : NT - 1) * BKB;                             \
    const int pc  = ((u) + 3) & 3;                                               \
    i32x4 aF[4], bF[4];                                                          \
    _Pragma("unroll")                                                            \
    for (int i = 0; i < 4; ++i) aF[i] = *(const i32x4*)&As[u][offA[i]];          \
    _Pragma("unroll")                                                            \
    for (int j = 0; j < 4; ++j) bF[j] = *(const i32x4*)&Bs[u][offB[j]];          \
    load16_to_lds(gA0 + pkt, &As[pc][ldw0]);                                     \
    load16_to_lds(gA1 + pkt, &As[pc][ldw1]);                                     \
    __builtin_amdgcn_s_barrier();                                                \
    asm volatile("s_waitcnt lgkmcnt(0)" ::: "memory");                           \
    __builtin_amdgcn_sched_barrier(0);                                           \
    __builtin_amdgcn_s_setprio(1);                                               \
    _Pragma("unroll")                                                            \
    for (int i = 0; i < 4; ++i)                                                  \
      _Pragma("unroll")                                                          \
      for (int j = 0; j < 4; ++j)                                                \
        ACC[i][j] = __builtin_amdgcn_mfma_i32_16x16x64_i8(aF[i], bF[j],          \
                                                          ACC[i][j], 0, 0, 0);   \
    __builtin_amdgcn_s_setprio(0);                                               \
    __builtin_amdgcn_s_barrier();                                                \
    i32x4 aG[4];                                                                 \
    _Pragma("unroll")                                                            \
    for (int i = 0; i < 4; ++i) aG[i] = *(const i32x4*)&As[u][offA[4 + i]];      \
    load16_to_lds(gB0 + pkt, &Bs[pc][ldw0]);                                     \
    load16_to_lds(gB1 + pkt, &Bs[pc][ldw1]);                                     \
    __builtin_amdgcn_s_barrier();                                                \
    asm volatile("s_waitcnt lgkmcnt(0)" ::: "memory");                           \
    __builtin_amdgcn_sched_barrier(0);                                           \
    __builtin_amdgcn_s_setprio(1);                                               \
    _Pragma("unroll")                                                            \
    for (int i = 0; i < 4; ++i)                                                  \
      _Pragma("unroll")                                                          \
      for (int j = 0; j < 4; ++j)                                                \
        ACC[4 + i][j] = __builtin_amdgcn_mfma_i32_16x16x64_i8(aG[i], bF[j],      \
                                                              ACC[4 + i][j] /*see note*/, 0, 0, 0); \
    __builtin_amdgcn_s_setprio(0);                                               \
    asm volatile("s_waitcnt vmcnt(8)" ::: "memory");                             \
    __builtin_amdgcn_s_barrier();                                                \
  }

  // Note: ACC has 8 row-frags (i=0..7): first 4 in phase A, last 4 in phase B.
  // Segments: tiles [0,32) -> accH8, [32,96) -> accM8, [96,128) -> accL8.
  // To keep acc arrays [8][4] semantics with 3 groups at [4][4] each declared
  // above is wrong -- redeclare properly as [8][4] per group would be 384 regs.
  // Instead: groups hold [8][4] halves split across H/M/L below.

  // --- we actually need [8][4] per group; use three [8][4] arrays is 384 regs.
  // Solution: per-wave output rows = 8 frags; gates quad packs 4 outputs per
  // reg slot, so acc is [8][4] i32x4 per group. Too many regs for 3 groups.
  // Restructure: per segment use a dedicated [8][4] array; compiler overlaps
  // liveness ONLY if we fold scale immediately. We fold each segment's acc
  // into f32 running gates right after its segment completes.
  (void)0;

  // f32 running gate accumulator (exact enough: each segment's i32 is exact,
  // fold adds 1 rounding per segment)
  float gacc[8][4][4];
#pragma unroll
  for (int i = 0; i < 8; ++i)
#pragma unroll
    for (int j = 0; j < 4; ++j)
#pragma unroll
      for (int r = 0; r < 4; ++r) gacc[i][j][r] = 0.f;

  {
    i32x4 acc[8][4];
#pragma unroll
    for (int i = 0; i < 8; ++i)
#pragma unroll
      for (int j = 0; j < 4; ++j) acc[i][j] = (i32x4){0, 0, 0, 0};
    for (int t4 = 0; t4 < 32; t4 += 4) {
#pragma unroll
      for (int u = 0; u < 4; ++u) { const int tt = t4 + u; KTILE_BODY(acc, tt, u) }
    }
#pragma unroll
    for (int i = 0; i < 8; ++i)
#pragma unroll
      for (int j = 0; j < 4; ++j)
#pragma unroll
        for (int r = 0; r < 4; ++r) gacc[i][j][r] += (float)acc[i][j][r];
  }
  {
    i32x4 acc[8][4];
#pragma unroll
    for (int i = 0; i < 8; ++i)
#pragma unroll
      for (int j = 0; j < 4; ++j) acc[i][j] = (i32x4){0, 0, 0, 0};
    for (int t4 = 32; t4 < 96; t4 += 4) {
#pragma unroll
      for (int u = 0; u < 4; ++u) { const int tt = t4 + u; KTILE_BODY(acc, tt, u) }
    }
#pragma unroll
    for (int i = 0; i < 8; ++i)
#pragma unroll
      for (int j = 0; j < 4; ++j)
#pragma unroll
        for (int r = 0; r < 4; ++r) gacc[i][j][r] += (float)acc[i][j][r] * (1.f / 254.f);
  }
  {
    i32x4 acc[8][4];
#pragma unroll
    for (int i = 0; i < 8; ++i)
#pragma unroll
      for (int j = 0; j < 4; ++j) acc[i][j] = (i32x4){0, 0, 0, 0};
    for (int t4 = 96; t4 < NT; t4 += 4) {
#pragma unroll
      for (int u = 0; u < 4; ++u) { const int tt = t4 + u; KTILE_BODY(acc, tt, u) }
    }
#pragma unroll
    for (int i = 0; i < 8; ++i)
#pragma unroll
      for (int j = 0; j < 4; ++j)
#pragma unroll
        for (int r = 0; r < 4; ++r) gacc[i][j][r] += (float)acc[i][j][r] * (1.f / 64516.f);
  }
#undef KTILE_BODY

  // epilogue: reg r = gate r (f,i,c,o) of (h, m); scale by s_x*s_w, add bias
  const float ST2 = SCALE * SCALE;
  const int n_base = n0 + (wm << 7);
  const int m_base = m0 + (wn << 6);
#pragma unroll
  for (int i = 0; i < 8; ++i) {
    int nf = n_base + i * 16 + ((l >> 4) << 2);
    int hq = nf >> 2;
    float4 b4 = *(const float4*)&bcat[nf];
#pragma unroll
    for (int j = 0; j < 4; ++j) {
      int m = m_base + j * 16 + fr;
      float ft = sigmoid_f(gacc[i][j][0] * ST2 + b4.x);
      float it = sigmoid_f(gacc[i][j][1] * ST2 + b4.y);
      float ct = tanh_f   (gacc[i][j][2] * ST2 + b4.z);
      float ot = sigmoid_f(gacc[i][j][3] * ST2 + b4.w);
      float cp = c_prev[(size_t)m * HID + hq];
      float cn = ft * cp + it * ct;
      out[(size_t)m * HID + hq] = ot * tanh_f(cn);
    }
  }
}

extern "C" void kernel_launch(void* const* d_in, const int* in_sizes, int n_in,
                              void* d_out, int out_size, void* d_ws, size_t ws_size,
                              hipStream_t stream) {
  const float* x  = (const float*)d_in[0];
  const float* hp = (const float*)d_in[1];
  const float* cp = (const float*)d_in[2];
  const float* Wf = (const float*)d_in[3];
  const float* Wi = (const float*)d_in[4];
  const float* Wc = (const float*)d_in[5];
  const float* Wo = (const float*)d_in[6];
  const float* Uf = (const float*)d_in[7];
  const float* Ui = (const float*)d_in[8];
  const float* Uc = (const float*)d_in[9];
  const float* Uo = (const float*)d_in[10];
  const float* bf = (const float*)d_in[11];
  const float* bi = (const float*)d_in[12];
  const float* bc = (const float*)d_in[13];
  const float* bo = (const float*)d_in[14];

  const size_t P_BYTES  = (size_t)NGATE * K8;   // 32 MiB
  const size_t BT_BYTES = (size_t)BATCH * K8;   // 32 MiB
  i8*    Pw   = (i8*)d_ws;
  i8*    Bt   = (i8*)((char*)d_ws + P_BYTES);
  float* bcat = (float*)((char*)d_ws + P_BYTES + BT_BYTES);
  float* out  = (float*)d_out;

  pack_act <<<dim3(8192), dim3(256), 0, stream>>>(x, hp, Bt);
  pack_w   <<<dim3(8192), dim3(256), 0, stream>>>(Wf, Wi, Wc, Wo, Uf, Ui, Uc, Uo, Pw);
  pack_bias<<<dim3(16),   dim3(256), 0, stream>>>(bf, bi, bc, bo, bcat);
  lstm_gemm<<<dim3(256),  dim3(512), 0, stream>>>(Pw, Bt, bcat, cp, out);
}

// Round 6
// 227.951 us; speedup vs baseline: 1.0774x; 1.0334x over previous
//
#include <hip/hip_runtime.h>

typedef unsigned short u16;
typedef __attribute__((ext_vector_type(8))) short bf16x8;
typedef __attribute__((ext_vector_type(4))) float f32x4;

#define HID 1024
#define BATCH 4096
#define K3 6144   // 3 * 2048 (hi | lo | hi split blocks)
#define NGATE 4096
#define BK 64     // K-step; two k-subtiles of 32
#define NT 96     // K3 / BK

// ---------- bf16 helpers ----------
__device__ __forceinline__ u16 f2bf(float f) {
  unsigned int u = __float_as_uint(f);
  u += 0x7FFFu + ((u >> 16) & 1u);   // RNE
  return (u16)(u >> 16);
}
__device__ __forceinline__ float bf2f(u16 h) {
  return __uint_as_float(((unsigned int)h) << 16);
}

__device__ __forceinline__ void load16_to_lds(const void* g, void* l) {
  __builtin_amdgcn_global_load_lds(
      (const __attribute__((address_space(1))) unsigned int*)g,
      (__attribute__((address_space(3))) unsigned int*)l, 16, 0, 0);
}

__device__ __forceinline__ float sigmoid_f(float x) {
  return 1.f / (1.f + __expf(-x));
}
__device__ __forceinline__ float tanh_f(float x) {
  return 1.f - 2.f / (__expf(2.f * x) + 1.f);
}

// ---------- pack activations: Bt[m][k'] = [hi(x|h) | lo(x|h) | hi(x|h)] ----------
__global__ void pack_act(const float* __restrict__ x, const float* __restrict__ h,
                         u16* __restrict__ Bt) {
  size_t idx = (size_t)blockIdx.x * 256 + threadIdx.x;
  int m  = (int)(idx >> 9);
  int kq = (int)(idx & 511) << 2;
  const float* src = (kq < 1024) ? (x + (size_t)m * 1024 + kq)
                                 : (h + (size_t)m * 1024 + (kq - 1024));
  float4 v = *(const float4*)src;
  ushort4 hi, lo;
  hi.x = f2bf(v.x); lo.x = f2bf(v.x - bf2f(hi.x));
  hi.y = f2bf(v.y); lo.y = f2bf(v.y - bf2f(hi.y));
  hi.z = f2bf(v.z); lo.z = f2bf(v.z - bf2f(hi.z));
  hi.w = f2bf(v.w); lo.w = f2bf(v.w - bf2f(hi.w));
  u16* row = Bt + (size_t)m * K3;
  *(ushort4*)(row + kq)        = hi;
  *(ushort4*)(row + 2048 + kq) = lo;
  *(ushort4*)(row + 4096 + kq) = hi;
}

// ---------- pack weights: P[n=4h+g][k'] = [hi(W;U) | hi(W;U) | lo(W;U)] ----------
__global__ void pack_w(const float* __restrict__ Wf, const float* __restrict__ Wi,
                       const float* __restrict__ Wc, const float* __restrict__ Wo,
                       const float* __restrict__ Uf, const float* __restrict__ Ui,
                       const float* __restrict__ Uc, const float* __restrict__ Uo,
                       u16* __restrict__ P) {
  __shared__ float ldsT[32][33];
  int bid = blockIdx.x;
  int mat = bid >> 10;
  int tid = bid & 1023;
  int k0 = (tid >> 5) << 5;
  int h0 = (tid & 31) << 5;
  int g = mat & 3;
  const float* S;
  {
    const float* a = (mat & 1) ? ((mat & 2) ? Wo : Wi) : ((mat & 2) ? Wc : Wf);
    const float* b = (mat & 1) ? ((mat & 2) ? Uo : Ui) : ((mat & 2) ? Uc : Uf);
    S = (mat & 4) ? b : a;
  }
  int kbase = (mat & 4) ? 1024 : 0;

  int t = threadIdx.x;
  {
    int r0 = t >> 5;
    int c  = t & 31;
#pragma unroll
    for (int j = 0; j < 4; ++j)
      ldsT[c][r0 + 8 * j] = S[(size_t)(k0 + r0 + 8 * j) * 1024 + h0 + c];
  }
  __syncthreads();
  {
    int c  = t >> 3;
    int kq = (t & 7) << 2;
    int n  = ((h0 + c) << 2) + g;
    float v0 = ldsT[c][kq + 0], v1 = ldsT[c][kq + 1];
    float v2 = ldsT[c][kq + 2], v3 = ldsT[c][kq + 3];
    ushort4 hi, lo;
    hi.x = f2bf(v0); lo.x = f2bf(v0 - bf2f(hi.x));
    hi.y = f2bf(v1); lo.y = f2bf(v1 - bf2f(hi.y));
    hi.z = f2bf(v2); lo.z = f2bf(v2 - bf2f(hi.z));
    hi.w = f2bf(v3); lo.w = f2bf(v3 - bf2f(hi.w));
    u16* base = P + (size_t)n * K3 + kbase + k0 + kq;
    *(ushort4*)(base)        = hi;
    *(ushort4*)(base + 2048) = hi;
    *(ushort4*)(base + 4096) = lo;
  }
}

// ---------- pack biases ----------
__global__ void pack_bias(const float* __restrict__ bf, const float* __restrict__ bi,
                          const float* __restrict__ bc, const float* __restrict__ bo,
                          float* __restrict__ bcat) {
  int i = blockIdx.x * 256 + threadIdx.x;
  if (i < NGATE) {
    int h = i >> 2, g = i & 3;
    const float* b = (g == 0) ? bf : (g == 1) ? bi : (g == 2) ? bc : bo;
    bcat[i] = b[h];
  }
}

// ---------- fused GEMM + LSTM epilogue ----------
// 256x256 tile, BK=64 as two k-subtiles (s0,s1), 8 waves (2n x 4m), dbuf LDS,
// 4 phases/tile split by (k-subtile x acc-half); staging partitioned along K so
// each phase depends on exactly one s-group; vmcnt(4) checkpoints at pB/pD.
__global__ __launch_bounds__(512, 2) void lstm_gemm(
    const u16* __restrict__ P, const u16* __restrict__ Bt,
    const float* __restrict__ bcat, const float* __restrict__ c_prev,
    float* __restrict__ out) {
  // [dbuf][k-subtile][256 rows x 32 elems(64B)] -> 64 KiB each of A,B
  __shared__ __align__(16) u16 As[2][2][8192];
  __shared__ __align__(16) u16 Bs[2][2][8192];

  const int t = threadIdx.x;
  const int w = t >> 6;
  const int l = t & 63;

  // XCD-chunked bijective block swizzle (256 = 8 XCD * 32)
  const int bid = blockIdx.x;
  const int swz = ((bid & 7) << 5) + (bid >> 3);
  const int n0 = (swz & 15) << 8;
  const int m0 = (swz >> 4) << 8;

  const int wm = w >> 2;              // 0..1 : wave n-half (128 rows)
  const int wn = w & 3;               // 0..3 : wave m-quarter (64 rows)

  // ---- staging geometry (R2-proven pattern): thread t covers row t>>2 of the
  //      q=0 half (and +128 for q=1), 16B slot (t&3) XOR'd on the SOURCE side.
  const int srow = (w << 4) + (l >> 2);                  // = t>>2, 0..127
  const int ssl  = (((l & 3) ^ ((l >> 3) & 3)) << 3);    // src slot swizzle
  const u16* gA = P  + (size_t)(n0 + srow) * K3 + ssl;
  const u16* gB = Bt + (size_t)(m0 + srow) * K3 + ssl;
  const int dq = w << 9;              // wave-uniform LDS elem base (rows w*16..+15)

  // ---- fragment read offsets (R2-proven zero-conflict pattern) ----
  const int fr = l & 15;
  const int sl = l >> 4;
  int offA[8], offB[4];
#pragma unroll
  for (int i = 0; i < 8; ++i) {
    int ar = (wm << 7) + i * 16 + fr;
    offA[i] = ar * 32 + ((sl ^ ((ar >> 1) & 3)) << 3);
  }
#pragma unroll
  for (int j = 0; j < 4; ++j) {
    int br = (wn << 6) + j * 16 + fr;
    offB[j] = br * 32 + ((sl ^ ((br >> 1) & 3)) << 3);
  }

  f32x4 acc[8][4];
#pragma unroll
  for (int i = 0; i < 8; ++i)
#pragma unroll
    for (int j = 0; j < 4; ++j) acc[i][j] = (f32x4){0.f, 0.f, 0.f, 0.f};

  // ---- prologue: stage tile 0, s0 first, then s1 ----
  load16_to_lds(gA,                            &As[0][0][dq]);
  load16_to_lds(gA + (size_t)128 * K3,         &As[0][0][dq + 4096]);
  load16_to_lds(gB,                            &Bs[0][0][dq]);
  load16_to_lds(gB + (size_t)128 * K3,         &Bs[0][0][dq + 4096]);
  load16_to_lds(gA + 32,                       &As[0][1][dq]);
  load16_to_lds(gA + 32 + (size_t)128 * K3,    &As[0][1][dq + 4096]);
  load16_to_lds(gB + 32,                       &Bs[0][1][dq]);
  load16_to_lds(gB + 32 + (size_t)128 * K3,    &Bs[0][1][dq + 4096]);
  asm volatile("s_waitcnt vmcnt(4)" ::: "memory");   // s0(0) landed
  __builtin_amdgcn_s_barrier();

  bf16x8 aF[4], aG[4], bF[4];

#define PH_OPEN                                                                 \
    __builtin_amdgcn_s_barrier();                                               \
    asm volatile("s_waitcnt lgkmcnt(0)" ::: "memory");                          \
    __builtin_amdgcn_sched_barrier(0);                                          \
    __builtin_amdgcn_s_setprio(1);

#define PH_CLOSE                                                                \
    __builtin_amdgcn_s_setprio(0);                                              \
    __builtin_amdgcn_s_barrier();

#define PH_CLOSE_VM                                                             \
    __builtin_amdgcn_s_setprio(0);                                              \
    asm volatile("s_waitcnt vmcnt(4)" ::: "memory");                            \
    __builtin_amdgcn_s_barrier();

#define MFMA16(IB, AOP)                                                         \
  _Pragma("unroll")                                                             \
  for (int i = 0; i < 4; ++i)                                                   \
    _Pragma("unroll")                                                           \
    for (int j = 0; j < 4; ++j)                                                 \
      acc[(IB) + i][j] = __builtin_amdgcn_mfma_f32_16x16x32_bf16(               \
          AOP[i], bF[j], acc[(IB) + i][j], 0, 0, 0);

#define TILE_BODY(BUF, TT)                                                      \
  {                                                                             \
    const int pf = ((TT) + 1 < NT) ? (TT) + 1 : NT - 1;                         \
    const size_t pfk = (size_t)pf * BK;                                         \
    const int BN_ = (BUF) ^ 1;                                                  \
    /* pA: s0, acc rows 0-3; stage A-s0(T+1) */                                 \
    _Pragma("unroll")                                                           \
    for (int i = 0; i < 4; ++i) aF[i] = *(const bf16x8*)&As[BUF][0][offA[i]];   \
    _Pragma("unroll")                                                           \
    for (int j = 0; j < 4; ++j) bF[j] = *(const bf16x8*)&Bs[BUF][0][offB[j]];   \
    load16_to_lds(gA + pfk,                    &As[BN_][0][dq]);                \
    load16_to_lds(gA + pfk + (size_t)128 * K3, &As[BN_][0][dq + 4096]);         \
    PH_OPEN                                                                     \
    MFMA16(0, aF)                                                               \
    PH_CLOSE                                                                    \
    /* pB: s0, acc rows 4-7 (bF reused); stage B-s0(T+1) */                     \
    _Pragma("unroll")                                                           \
    for (int i = 0; i < 4; ++i) aG[i] = *(const bf16x8*)&As[BUF][0][offA[4+i]]; \
    load16_to_lds(gB + pfk,                    &Bs[BN_][0][dq]);                \
    load16_to_lds(gB + pfk + (size_t)128 * K3, &Bs[BN_][0][dq + 4096]);         \
    PH_OPEN                                                                     \
    MFMA16(4, aG)                                                               \
    PH_CLOSE_VM   /* drains s1(TT): needed by pC/pD */                          \
    /* pC: s1, acc rows 0-3; stage A-s1(T+1) */                                 \
    _Pragma("unroll")                                                           \
    for (int i = 0; i < 4; ++i) aF[i] = *(const bf16x8*)&As[BUF][1][offA[i]];   \
    _Pragma("unroll")                                                           \
    for (int j = 0; j < 4; ++j) bF[j] = *(const bf16x8*)&Bs[BUF][1][offB[j]];   \
    load16_to_lds(gA + pfk + 32,                    &As[BN_][1][dq]);           \
    load16_to_lds(gA + pfk + 32 + (size_t)128 * K3, &As[BN_][1][dq + 4096]);    \
    PH_OPEN                                                                     \
    MFMA16(0, aF)                                                               \
    PH_CLOSE                                                                    \
    /* pD: s1, acc rows 4-7; stage B-s1(T+1) */                                 \
    _Pragma("unroll")                                                           \
    for (int i = 0; i < 4; ++i) aG[i] = *(const bf16x8*)&As[BUF][1][offA[4+i]]; \
    load16_to_lds(gB + pfk + 32,                    &Bs[BN_][1][dq]);           \
    load16_to_lds(gB + pfk + 32 + (size_t)128 * K3, &Bs[BN_][1][dq + 4096]);    \
    PH_OPEN                                                                     \
    MFMA16(4, aG)                                                               \
    PH_CLOSE_VM   /* drains s0(TT+1): needed by next pA/pB */                   \
  }

  for (int T = 0; T < NT; T += 2) {
    TILE_BODY(0, T)
    TILE_BODY(1, T + 1)
  }
#undef TILE_BODY
#undef MFMA16
#undef PH_OPEN
#undef PH_CLOSE
#undef PH_CLOSE_VM

  asm volatile("s_waitcnt vmcnt(0)" ::: "memory");

  // ---- epilogue: lane regs r=0..3 are gates f,i,c,o of (h, m) ----
  const int n_base = n0 + (wm << 7);
  const int m_base = m0 + (wn << 6);
#pragma unroll
  for (int i = 0; i < 8; ++i) {
    int nf = n_base + i * 16 + ((l >> 4) << 2);
    int hq = nf >> 2;
    float4 b4 = *(const float4*)&bcat[nf];
#pragma unroll
    for (int j = 0; j < 4; ++j) {
      int m = m_base + j * 16 + fr;
      f32x4 a = acc[i][j];
      float ft = sigmoid_f(a[0] + b4.x);
      float it = sigmoid_f(a[1] + b4.y);
      float ct = tanh_f   (a[2] + b4.z);
      float ot = sigmoid_f(a[3] + b4.w);
      float cp = c_prev[(size_t)m * HID + hq];
      float cn = ft * cp + it * ct;
      out[(size_t)m * HID + hq] = ot * tanh_f(cn);
    }
  }
}

extern "C" void kernel_launch(void* const* d_in, const int* in_sizes, int n_in,
                              void* d_out, int out_size, void* d_ws, size_t ws_size,
                              hipStream_t stream) {
  const float* x  = (const float*)d_in[0];
  const float* hp = (const float*)d_in[1];
  const float* cp = (const float*)d_in[2];
  const float* Wf = (const float*)d_in[3];
  const float* Wi = (const float*)d_in[4];
  const float* Wc = (const float*)d_in[5];
  const float* Wo = (const float*)d_in[6];
  const float* Uf = (const float*)d_in[7];
  const float* Ui = (const float*)d_in[8];
  const float* Uc = (const float*)d_in[9];
  const float* Uo = (const float*)d_in[10];
  const float* bf = (const float*)d_in[11];
  const float* bi = (const float*)d_in[12];
  const float* bc = (const float*)d_in[13];
  const float* bo = (const float*)d_in[14];

  const size_t P_BYTES  = (size_t)NGATE * K3 * 2;   // 48 MiB
  const size_t BT_BYTES = (size_t)BATCH * K3 * 2;   // 48 MiB
  u16*   Pw   = (u16*)d_ws;
  u16*   Bt   = (u16*)((char*)d_ws + P_BYTES);
  float* bcat = (float*)((char*)d_ws + P_BYTES + BT_BYTES);
  float* out  = (float*)d_out;

  pack_act <<<dim3(8192), dim3(256), 0, stream>>>(x, hp, Bt);
  pack_w   <<<dim3(8192), dim3(256), 0, stream>>>(Wf, Wi, Wc, Wo, Uf, Ui, Uc, Uo, Pw);
  pack_bias<<<dim3(16),   dim3(256), 0, stream>>>(bf, bi, bc, bo, bcat);
  lstm_gemm<<<dim3(256),  dim3(512), 0, stream>>>(Pw, Bt, bcat, cp, out);
}

// Round 7
// 223.661 us; speedup vs baseline: 1.0981x; 1.0192x over previous
//
#include <hip/hip_runtime.h>

typedef unsigned short u16;
typedef __attribute__((ext_vector_type(8))) short bf16x8;
typedef __attribute__((ext_vector_type(4))) float f32x4;

#define HID 1024
#define BATCH 4096
#define K3 6144   // 3 * 2048 (hi | lo | hi split blocks)
#define NGATE 4096
#define BK 32
#define NT 192    // K3 / BK

// ---------- bf16 helpers ----------
__device__ __forceinline__ u16 f2bf(float f) {
  unsigned int u = __float_as_uint(f);
  u += 0x7FFFu + ((u >> 16) & 1u);   // RNE
  return (u16)(u >> 16);
}
__device__ __forceinline__ float bf2f(u16 h) {
  return __uint_as_float(((unsigned int)h) << 16);
}

__device__ __forceinline__ void load16_to_lds(const void* g, void* l) {
  __builtin_amdgcn_global_load_lds(
      (const __attribute__((address_space(1))) unsigned int*)g,
      (__attribute__((address_space(3))) unsigned int*)l, 16, 0, 0);
}

__device__ __forceinline__ float sigmoid_f(float x) {
  return 1.f / (1.f + __expf(-x));
}
__device__ __forceinline__ float tanh_f(float x) {
  return 1.f - 2.f / (__expf(2.f * x) + 1.f);
}

// ---------- pack activations: Bt[m][k'] = [hi(x|h) | lo(x|h) | hi(x|h)] ----------
__global__ void pack_act(const float* __restrict__ x, const float* __restrict__ h,
                         u16* __restrict__ Bt) {
  size_t idx = (size_t)blockIdx.x * 256 + threadIdx.x;
  int m  = (int)(idx >> 9);
  int kq = (int)(idx & 511) << 2;
  const float* src = (kq < 1024) ? (x + (size_t)m * 1024 + kq)
                                 : (h + (size_t)m * 1024 + (kq - 1024));
  float4 v = *(const float4*)src;
  ushort4 hi, lo;
  hi.x = f2bf(v.x); lo.x = f2bf(v.x - bf2f(hi.x));
  hi.y = f2bf(v.y); lo.y = f2bf(v.y - bf2f(hi.y));
  hi.z = f2bf(v.z); lo.z = f2bf(v.z - bf2f(hi.z));
  hi.w = f2bf(v.w); lo.w = f2bf(v.w - bf2f(hi.w));
  u16* row = Bt + (size_t)m * K3;
  *(ushort4*)(row + kq)        = hi;
  *(ushort4*)(row + 2048 + kq) = lo;
  *(ushort4*)(row + 4096 + kq) = hi;
}

// ---------- pack weights: P[n=4h+g][k'] = [hi(W;U) | hi(W;U) | lo(W;U)] ----------
__global__ void pack_w(const float* __restrict__ Wf, const float* __restrict__ Wi,
                       const float* __restrict__ Wc, const float* __restrict__ Wo,
                       const float* __restrict__ Uf, const float* __restrict__ Ui,
                       const float* __restrict__ Uc, const float* __restrict__ Uo,
                       u16* __restrict__ P) {
  __shared__ float ldsT[32][33];
  int bid = blockIdx.x;
  int mat = bid >> 10;
  int tid = bid & 1023;
  int k0 = (tid >> 5) << 5;
  int h0 = (tid & 31) << 5;
  int g = mat & 3;
  const float* S;
  {
    const float* a = (mat & 1) ? ((mat & 2) ? Wo : Wi) : ((mat & 2) ? Wc : Wf);
    const float* b = (mat & 1) ? ((mat & 2) ? Uo : Ui) : ((mat & 2) ? Uc : Uf);
    S = (mat & 4) ? b : a;
  }
  int kbase = (mat & 4) ? 1024 : 0;

  int t = threadIdx.x;
  {
    int r0 = t >> 5;
    int c  = t & 31;
#pragma unroll
    for (int j = 0; j < 4; ++j)
      ldsT[c][r0 + 8 * j] = S[(size_t)(k0 + r0 + 8 * j) * 1024 + h0 + c];
  }
  __syncthreads();
  {
    int c  = t >> 3;
    int kq = (t & 7) << 2;
    int n  = ((h0 + c) << 2) + g;
    float v0 = ldsT[c][kq + 0], v1 = ldsT[c][kq + 1];
    float v2 = ldsT[c][kq + 2], v3 = ldsT[c][kq + 3];
    ushort4 hi, lo;
    hi.x = f2bf(v0); lo.x = f2bf(v0 - bf2f(hi.x));
    hi.y = f2bf(v1); lo.y = f2bf(v1 - bf2f(hi.y));
    hi.z = f2bf(v2); lo.z = f2bf(v2 - bf2f(hi.z));
    hi.w = f2bf(v3); lo.w = f2bf(v3 - bf2f(hi.w));
    u16* base = P + (size_t)n * K3 + kbase + k0 + kq;
    *(ushort4*)(base)        = hi;
    *(ushort4*)(base + 2048) = hi;
    *(ushort4*)(base + 4096) = lo;
  }
}

// ---------- pack biases ----------
__global__ void pack_bias(const float* __restrict__ bf, const float* __restrict__ bi,
                          const float* __restrict__ bc, const float* __restrict__ bo,
                          float* __restrict__ bcat) {
  int i = blockIdx.x * 256 + threadIdx.x;
  if (i < NGATE) {
    int h = i >> 2, g = i & 3;
    const float* b = (g == 0) ? bf : (g == 1) ? bi : (g == 2) ? bc : bo;
    bcat[i] = b[h];
  }
}

// ---------- fused GEMM + LSTM epilogue ----------
// 256x256 tile, BK=32, 8 waves, 4-deep LDS ring, ONE sync per K-tile
// {lgkmcnt(0) + vmcnt(8) + s_barrier}; tile body is barrier-free straight-line
// {4 stage-issues, 12 ds_reads, 32 MFMA} for compiler-driven interleave.
__global__ __launch_bounds__(512, 2) void lstm_gemm(
    const u16* __restrict__ P, const u16* __restrict__ Bt,
    const float* __restrict__ bcat, const float* __restrict__ c_prev,
    float* __restrict__ out) {
  __shared__ __align__(16) u16 As[4][256 * BK];   // 64 KiB
  __shared__ __align__(16) u16 Bs[4][256 * BK];   // 64 KiB

  const int t = threadIdx.x;
  const int w = t >> 6;
  const int l = t & 63;

  // XCD-chunked bijective block swizzle (256 = 8 XCD * 32)
  const int bid = blockIdx.x;
  const int swz = ((bid & 7) << 5) + (bid >> 3);
  const int n0 = (swz & 15) << 8;     // gate-dim tile base
  const int m0 = (swz >> 4) << 8;     // batch tile base

  const int wm = w >> 2;              // 0..1 : wave n-half
  const int wn = w & 3;               // 0..3 : wave m-quarter

  // ---- staging: 4 x global_load_lds per K-tile per wave, swizzled source ----
  const int srow = t >> 2;                               // 0..127
  const int ssl  = (((t & 3) ^ ((srow >> 1) & 3)) << 3); // swizzled 8-u16 slot
  const u16* gA0 = P  + (size_t)(n0 + srow)       * K3 + ssl;
  const u16* gA1 = P  + (size_t)(n0 + 128 + srow) * K3 + ssl;
  const u16* gB0 = Bt + (size_t)(m0 + srow)       * K3 + ssl;
  const u16* gB1 = Bt + (size_t)(m0 + 128 + srow) * K3 + ssl;
  const int ldw0 = w << 9;            // wave-uniform LDS dest (u16)
  const int ldw1 = 4096 + (w << 9);

  // ---- fragment read offsets (loop-invariant, R2-proven zero-conflict) ----
  const int fr = l & 15;
  const int sl = l >> 4;
  int offA[8], offB[4];
#pragma unroll
  for (int i = 0; i < 8; ++i) {
    int ar = (wm << 7) + i * 16 + fr;
    offA[i] = ar * BK + ((sl ^ ((ar >> 1) & 3)) << 3);
  }
#pragma unroll
  for (int j = 0; j < 4; ++j) {
    int br = (wn << 6) + j * 16 + fr;
    offB[j] = br * BK + ((sl ^ ((br >> 1) & 3)) << 3);
  }

  f32x4 acc[8][4];
#pragma unroll
  for (int i = 0; i < 8; ++i)
#pragma unroll
    for (int j = 0; j < 4; ++j) acc[i][j] = (f32x4){0.f, 0.f, 0.f, 0.f};

  // ---- prologue: stage K-tiles 0,1,2 into bufs 0,1,2 ----
#pragma unroll
  for (int pt = 0; pt < 3; ++pt) {
    const int kt = pt * BK;
    load16_to_lds(gA0 + kt, &As[pt][ldw0]);
    load16_to_lds(gA1 + kt, &As[pt][ldw1]);
    load16_to_lds(gB0 + kt, &Bs[pt][ldw0]);
    load16_to_lds(gB1 + kt, &Bs[pt][ldw1]);
  }

  // ---- main loop: 192 K-tiles, unrolled x4 for static ring indices ----
  for (int t4 = 0; t4 < NT; t4 += 4) {
#pragma unroll
    for (int u = 0; u < 4; ++u) {
      const int tt  = t4 + u;
      const int pfi = tt + 3;
      const int pkt = (pfi < NT ? pfi : NT - 1) * BK;  // clamped tail prefetch
      const int pc  = (u + 3) & 3;

      // ---- single sync point per tile ----
      // lgkmcnt(0): all waves' reads of buf[(tt-1)&3] returned (stage(tt)
      //             overwrites that buffer 3 tiles ahead).
      // vmcnt(8):   tile tt's 4 stages landed; tiles tt+1,tt+2 (8) in flight.
      asm volatile("s_waitcnt lgkmcnt(0)" ::: "memory");
      asm volatile("s_waitcnt vmcnt(8)" ::: "memory");
      __builtin_amdgcn_s_barrier();
      __builtin_amdgcn_sched_barrier(0);

      // stage tile tt+3 into buf[(tt+3)&3]
      load16_to_lds(gA0 + pkt, &As[pc][ldw0]);
      load16_to_lds(gA1 + pkt, &As[pc][ldw1]);
      load16_to_lds(gB0 + pkt, &Bs[pc][ldw0]);
      load16_to_lds(gB1 + pkt, &Bs[pc][ldw1]);

      // reads + MFMA: no barriers; compiler interleaves via fine lgkmcnt
      bf16x8 aF[4], aG[4], bF[4];
#pragma unroll
      for (int i = 0; i < 4; ++i) aF[i] = *(const bf16x8*)&As[u][offA[i]];
#pragma unroll
      for (int j = 0; j < 4; ++j) bF[j] = *(const bf16x8*)&Bs[u][offB[j]];
#pragma unroll
      for (int i = 0; i < 4; ++i) aG[i] = *(const bf16x8*)&As[u][offA[4 + i]];

      __builtin_amdgcn_s_setprio(1);
#pragma unroll
      for (int i = 0; i < 4; ++i)
#pragma unroll
        for (int j = 0; j < 4; ++j)
          acc[i][j] = __builtin_amdgcn_mfma_f32_16x16x32_bf16(aF[i], bF[j], acc[i][j], 0, 0, 0);
#pragma unroll
      for (int i = 0; i < 4; ++i)
#pragma unroll
        for (int j = 0; j < 4; ++j)
          acc[4 + i][j] = __builtin_amdgcn_mfma_f32_16x16x32_bf16(aG[i], bF[j], acc[4 + i][j], 0, 0, 0);
      __builtin_amdgcn_s_setprio(0);
    }
  }

  // ---- epilogue: lane regs r=0..3 are gates f,i,c,o of (h, m) ----
  const int n_base = n0 + (wm << 7);
  const int m_base = m0 + (wn << 6);
#pragma unroll
  for (int i = 0; i < 8; ++i) {
    int nf = n_base + i * 16 + ((l >> 4) << 2);
    int hq = nf >> 2;
    float4 b4 = *(const float4*)&bcat[nf];
#pragma unroll
    for (int j = 0; j < 4; ++j) {
      int m = m_base + j * 16 + fr;
      f32x4 a = acc[i][j];
      float ft = sigmoid_f(a[0] + b4.x);
      float it = sigmoid_f(a[1] + b4.y);
      float ct = tanh_f   (a[2] + b4.z);
      float ot = sigmoid_f(a[3] + b4.w);
      float cp = c_prev[(size_t)m * HID + hq];
      float cn = ft * cp + it * ct;
      out[(size_t)m * HID + hq] = ot * tanh_f(cn);
    }
  }
}

extern "C" void kernel_launch(void* const* d_in, const int* in_sizes, int n_in,
                              void* d_out, int out_size, void* d_ws, size_t ws_size,
                              hipStream_t stream) {
  const float* x  = (const float*)d_in[0];
  const float* hp = (const float*)d_in[1];
  const float* cp = (const float*)d_in[2];
  const float* Wf = (const float*)d_in[3];
  const float* Wi = (const float*)d_in[4];
  const float* Wc = (const float*)d_in[5];
  const float* Wo = (const float*)d_in[6];
  const float* Uf = (const float*)d_in[7];
  const float* Ui = (const float*)d_in[8];
  const float* Uc = (const float*)d_in[9];
  const float* Uo = (const float*)d_in[10];
  const float* bf = (const float*)d_in[11];
  const float* bi = (const float*)d_in[12];
  const float* bc = (const float*)d_in[13];
  const float* bo = (const float*)d_in[14];

  const size_t P_BYTES  = (size_t)NGATE * K3 * 2;   // 48 MiB
  const size_t BT_BYTES = (size_t)BATCH * K3 * 2;   // 48 MiB
  u16*   Pw   = (u16*)d_ws;
  u16*   Bt   = (u16*)((char*)d_ws + P_BYTES);
  float* bcat = (float*)((char*)d_ws + P_BYTES + BT_BYTES);
  float* out  = (float*)d_out;

  pack_act <<<dim3(8192), dim3(256), 0, stream>>>(x, hp, Bt);
  pack_w   <<<dim3(8192), dim3(256), 0, stream>>>(Wf, Wi, Wc, Wo, Uf, Ui, Uc, Uo, Pw);
  pack_bias<<<dim3(16),   dim3(256), 0, stream>>>(bf, bi, bc, bo, bcat);
  lstm_gemm<<<dim3(256),  dim3(512), 0, stream>>>(Pw, Bt, bcat, cp, out);
}